// Round 12
// baseline (1043.512 us; speedup 1.0000x reference)
//
#include <hip/hip_runtime.h>
#include <hip/hip_bf16.h>

#define T_TOK 2048
#define D_HID 2048
#define F_INT 1408
#define N_EXP 32
#define TOPK 6
#define NJOBS 34
#define SH_BASE 12288
#define ROWS_TOTAL 16384
#define XP_ROWS 14336
#define MAXT_GU 159
#define GU_NBN 22
#define MAXT_DN 159
#define LDSW 40                // B LDS row stride (80 B)

typedef __bf16 bf16;
typedef __bf16 bf16x4 __attribute__((ext_vector_type(4)));
typedef __bf16 bf16x8 __attribute__((ext_vector_type(8)));
typedef float f32x4 __attribute__((ext_vector_type(4)));

// lgkm-only barrier: B dbuf hazard protection; VMEM loads stay in flight.
#define BAR() asm volatile("s_waitcnt lgkmcnt(0)\n\ts_barrier" ::: "memory")

// B swizzle (R8-verified: writes/reads at bank floor)
__device__ __forceinline__ int swz16(int r, int k) {
    return r * LDSW + ((((k >> 3) ^ ((r >> 3) & 3) ^ ((r >> 5) & 3)) & 3) << 3) + (k & 7);
}

__device__ __forceinline__ int decode_tile(const int* __restrict__ counts, int bid,
                                           int NBN, int MSH, int NSH,
                                           int& job, int& n0, int& m0) {
    int total = 0;
    for (int j = 0; j < NJOBS; ++j) {
        int c = (j < N_EXP) ? counts[j] : T_TOK;
        total += ((c + (1 << MSH) - 1) >> MSH) * NBN;
    }
    if (bid >= total) return 0;
    int q = total >> 3, r = total & 7, x = bid & 7, o = bid >> 3;
    int L = (x < r ? x * (q + 1) : r * (q + 1) + (x - r) * q) + o;
    int acc = 0;
    for (int j = 0; j < NJOBS; ++j) {
        int c = (j < N_EXP) ? counts[j] : T_TOK;
        int tc = (c + (1 << MSH) - 1) >> MSH;
        int b = tc * NBN;
        if (L < acc + b) {
            int rem = L - acc;
            int n0i = rem / tc;
            job = j;
            n0 = n0i << NSH;
            m0 = (rem - n0i * tc) << MSH;
            return 1;
        }
        acc += b;
    }
    return 0;
}

// ---------------- router ----------------
__global__ __launch_bounds__(256) void k_router(const float* __restrict__ x,
                                                const float* __restrict__ wr,
                                                int* __restrict__ counts,
                                                int* __restrict__ tok_e,
                                                float* __restrict__ tok_w) {
    int t = blockIdx.x;
    int tid = threadIdx.x;
    __shared__ float xs[D_HID];
    __shared__ float part[8][32];
    __shared__ float probs[N_EXP];

    const float4* xsrc = (const float4*)(x + (size_t)t * D_HID);
    float4* xdst = (float4*)xs;
    for (int i = tid; i < D_HID / 4; i += 256) xdst[i] = xsrc[i];
    __syncthreads();

    int e = tid & 31, c = tid >> 5;
    float p = 0.f;
    const float* wp = wr + e;
    #pragma unroll 8
    for (int h = c * 256; h < c * 256 + 256; ++h) p += xs[h] * wp[h * 32];
    part[c][e] = p;
    __syncthreads();

    if (tid < 32) {
        float l = 0.f;
        #pragma unroll
        for (int cc = 0; cc < 8; ++cc) l += part[cc][tid];
        float m = l;
        for (int off = 16; off; off >>= 1) m = fmaxf(m, __shfl_xor(m, off));
        float ex = __expf(l - m);
        float s = ex;
        for (int off = 16; off; off >>= 1) s += __shfl_xor(s, off);
        probs[tid] = ex / s;
    }
    __syncthreads();

    if (tid == 0) {
        unsigned used = 0;
        int ids[TOPK]; float wsv[TOPK]; float wsum = 0.f;
        for (int k = 0; k < TOPK; ++k) {
            int best = 0; float bv = -1.f;
            for (int ee = 0; ee < N_EXP; ++ee)
                if (!((used >> ee) & 1u) && probs[ee] > bv) { bv = probs[ee]; best = ee; }
            used |= 1u << best;
            ids[k] = best; wsv[k] = bv; wsum += bv;
        }
        float inv = 1.f / wsum;
        for (int k = 0; k < TOPK; ++k) {
            tok_e[t * TOPK + k] = ids[k];
            tok_w[t * TOPK + k] = wsv[k] * inv;
            atomicAdd(&counts[ids[k]], 1);
        }
    }
}

// ---------------- plan ----------------
__global__ void k_plan(const int* __restrict__ counts, int* __restrict__ offs,
                       int* __restrict__ cursors) {
    int tid = threadIdx.x;
    if (tid < N_EXP) cursors[tid] = 0;
    if (tid == 0) {
        int o = 0;
        offs[0] = 0;
        for (int e2 = 0; e2 < N_EXP; ++e2) { o += counts[e2]; offs[e2 + 1] = o; }
        offs[33] = offs[32] + T_TOK;
        offs[34] = offs[33] + T_TOK;
    }
}

// ---------------- assign ----------------
__global__ __launch_bounds__(256) void k_assign(const int* __restrict__ tok_e,
                                                const int* __restrict__ offs,
                                                int* __restrict__ cursors,
                                                int* __restrict__ slots,
                                                int* __restrict__ rowtok) {
    int t = blockIdx.x * 256 + threadIdx.x;
    #pragma unroll
    for (int k = 0; k < TOPK; ++k) {
        int e = tok_e[t * TOPK + k];
        int pos = atomicAdd(&cursors[e], 1);
        int slot = offs[e] + pos;
        slots[t * TOPK + k] = slot;
        rowtok[slot] = t;
    }
    rowtok[SH_BASE + t] = t;
    rowtok[SH_BASE + T_TOK + t] = t;
}

// ---------------- gather+cvt ----------------
__global__ __launch_bounds__(256) void k_gather(const float* __restrict__ x,
                                                const int* __restrict__ rowtok,
                                                bf16* __restrict__ Xp) {
    int s = blockIdx.x;
    int src = (s < SH_BASE) ? rowtok[s] : (s - SH_BASE);
    const float* xr = x + (size_t)src * D_HID + threadIdx.x * 8;
    float4 f0 = *(const float4*)xr;
    float4 f1 = *(const float4*)(xr + 4);
    bf16x8 v = {(bf16)f0.x, (bf16)f0.y, (bf16)f0.z, (bf16)f0.w,
                (bf16)f1.x, (bf16)f1.y, (bf16)f1.z, (bf16)f1.w};
    *(bf16x8*)(Xp + (size_t)s * D_HID + threadIdx.x * 8) = v;
}

__global__ __launch_bounds__(256) void k_xcvt(const float* __restrict__ x,
                                              bf16* __restrict__ xb) {
    int i = blockIdx.x * 2048 + threadIdx.x * 8;
    float4 f0 = *(const float4*)(x + i);
    float4 f1 = *(const float4*)(x + i + 4);
    bf16x8 v = {(bf16)f0.x, (bf16)f0.y, (bf16)f0.z, (bf16)f0.w,
                (bf16)f1.x, (bf16)f1.y, (bf16)f1.z, (bf16)f1.w};
    *(bf16x8*)(xb + i) = v;
}

// ---------------- GEMM1: H = silu(X Wg) * (X Wu) ----------------
// BM=128 x BN=64, BK=32, 4 waves (wave 64x32 of both mats, acc=64 AGPR).
// A-frags loaded DIRECTLY from global (L2-hot: 22 n-siblings + wave pairs
// share rows; each frag-load = 16 full 64B segments). LDS holds B only (20KB)
// -> per-CU LDS demand nearly halves (the R11 bottleneck).
__global__ __launch_bounds__(256, 3) void k_gateup(
    const bf16* __restrict__ xp, const float* __restrict__ wg, const float* __restrict__ wu,
    const float* __restrict__ sg, const float* __restrict__ su,
    const int* __restrict__ rowtok, const int* __restrict__ counts, const int* __restrict__ offs,
    bf16* __restrict__ H, int dense) {

    int job, n0, m0;
    if (!decode_tile(counts, blockIdx.x, GU_NBN, 7, 6, job, n0, m0)) return;
    int cnt = (job < N_EXP) ? counts[job] : T_TOK;
    int base = offs[job];
    const float* Wg = (job < N_EXP) ? wg + (size_t)job * D_HID * F_INT
                                    : sg + (size_t)(job - N_EXP) * D_HID * F_INT;
    const float* Wu = (job < N_EXP) ? wu + (size_t)job * D_HID * F_INT
                                    : su + (size_t)(job - N_EXP) * D_HID * F_INT;

    __shared__ bf16 Bg[2][64 * LDSW];        // 10 KB
    __shared__ bf16 Bu[2][64 * LDSW];        // 10 KB

    int tid = threadIdx.x;
    int lane = tid & 63;
    int wid = tid >> 6;
    int wm = (wid & 1) * 64;
    int wn = (wid >> 1) * 32;
    int q = lane >> 4;

    // per-frag A global base pointers (loop-invariant, clamped rows)
    const bf16* aptr[4];
    #pragma unroll
    for (int mf = 0; mf < 4; ++mf) {
        int R = wm + mf * 16 + (lane & 15);
        int grow = m0 + R; if (grow > cnt - 1) grow = cnt - 1;
        int arow = dense ? (((job < N_EXP) ? base : SH_BASE) + grow)
                         : rowtok[base + grow];
        aptr[mf] = xp + (size_t)arow * D_HID + q * 8;
    }

    // B staging: half threads Wg / half Wu; n-fastest coalesced
    int sub = tid & 127;
    int nn = (sub & 15) * 4;
    int k4 = (sub >> 4) * 4;
    const float* wsrc = ((tid & 128) ? Wu : Wg) + (size_t)k4 * F_INT + n0 + nn;

    int boff[2];
    #pragma unroll
    for (int nf = 0; nf < 2; ++nf)
        boff[nf] = swz16(wn + nf * 16 + (lane & 15), q * 8);

    f32x4 accg[4][2], accu[4][2];
    f32x4 zero = {0.f, 0.f, 0.f, 0.f};
    #pragma unroll
    for (int i = 0; i < 4; ++i)
        #pragma unroll
        for (int j = 0; j < 2; ++j) { accg[i][j] = zero; accu[i][j] = zero; }

    bf16x8 af[4];
    float4 rb[4];

    auto LOADAF = [&](int kt) {
        #pragma unroll
        for (int mf = 0; mf < 4; ++mf)
            af[mf] = *(const bf16x8*)(aptr[mf] + kt * 32);
    };
    auto LOADB = [&](int t) {
        const float* b0 = wsrc + (size_t)(t * 32) * F_INT;
        rb[0] = *(const float4*)b0;
        rb[1] = *(const float4*)(b0 + F_INT);
        rb[2] = *(const float4*)(b0 + 2 * F_INT);
        rb[3] = *(const float4*)(b0 + 3 * F_INT);
    };
    auto WRITEB = [&](int s) {
        bf16* bd = (tid & 128) ? Bu[s] : Bg[s];
        bf16x4 p0 = {(bf16)rb[0].x, (bf16)rb[1].x, (bf16)rb[2].x, (bf16)rb[3].x};
        bf16x4 p1 = {(bf16)rb[0].y, (bf16)rb[1].y, (bf16)rb[2].y, (bf16)rb[3].y};
        bf16x4 p2 = {(bf16)rb[0].z, (bf16)rb[1].z, (bf16)rb[2].z, (bf16)rb[3].z};
        bf16x4 p3 = {(bf16)rb[0].w, (bf16)rb[1].w, (bf16)rb[2].w, (bf16)rb[3].w};
        *(bf16x4*)&bd[swz16(nn + 0, k4)] = p0;
        *(bf16x4*)&bd[swz16(nn + 1, k4)] = p1;
        *(bf16x4*)&bd[swz16(nn + 2, k4)] = p2;
        *(bf16x4*)&bd[swz16(nn + 3, k4)] = p3;
    };
    auto MM = [&](int cur) {
        #pragma unroll
        for (int nf = 0; nf < 2; ++nf) {
            bf16x8 bfr = *(const bf16x8*)&Bg[cur][boff[nf]];
            bf16x8 ufr = *(const bf16x8*)&Bu[cur][boff[nf]];
            #pragma unroll
            for (int mf = 0; mf < 4; ++mf) {
                accg[mf][nf] = __builtin_amdgcn_mfma_f32_16x16x32_bf16(af[mf], bfr, accg[mf][nf], 0, 0, 0);
                accu[mf][nf] = __builtin_amdgcn_mfma_f32_16x16x32_bf16(af[mf], ufr, accu[mf][nf], 0, 0, 0);
            }
        }
    };

    const int NT = D_HID / 32;   // 64
    LOADB(0);
    WRITEB(0);
    LOADB(1);
    BAR();

    for (int kt = 0; kt < NT; ++kt) {
        int cur = kt & 1, nxt = cur ^ 1;
        LOADAF(kt);                              // issue early: covered by WRITEB+LOADB+B-reads
        if (kt + 1 < NT) WRITEB(nxt);            // retires rb (FIFO-older than af)
        if (kt + 2 < NT) LOADB(kt + 2);          // stays in flight across barrier
        MM(cur);                                 // compiler waits af just before MFMA
        BAR();                                   // lgkm-only: B dbuf hazard
    }

    // epilogue: h = silu(g) * u
    #pragma unroll
    for (int mf = 0; mf < 4; ++mf) {
        #pragma unroll
        for (int nf = 0; nf < 2; ++nf) {
            int col = n0 + wn + nf * 16 + (lane & 15);
            #pragma unroll
            for (int r = 0; r < 4; ++r) {
                int grow = m0 + wm + mf * 16 + (lane >> 4) * 4 + r;
                if (grow < cnt) {
                    float g = accg[mf][nf][r];
                    float u = accu[mf][nf][r];
                    float h = g * u / (1.f + __expf(-g));
                    H[(size_t)(base + grow) * F_INT + col] = (bf16)h;
                }
            }
        }
    }
}

// ---------------- GEMM2: P = H Wd ----------------
// 128x128, BK=32, 4 waves of 64x64; A-frags direct from H (global, L2-hot).
__global__ __launch_bounds__(256, 3) void k_down(
    const bf16* __restrict__ H, const float* __restrict__ wd, const float* __restrict__ sd,
    const int* __restrict__ counts, const int* __restrict__ offs,
    bf16* __restrict__ P) {

    int job, n0, m0;
    if (!decode_tile(counts, blockIdx.x, D_HID / 128, 7, 7, job, n0, m0)) return;
    int cnt = (job < N_EXP) ? counts[job] : T_TOK;
    int base = offs[job];
    const float* Wd = (job < N_EXP) ? wd + (size_t)job * F_INT * D_HID
                                    : sd + (size_t)(job - N_EXP) * F_INT * D_HID;

    __shared__ bf16 Bs[2][128 * LDSW];       // 20 KB

    int tid = threadIdx.x;
    int lane = tid & 63;
    int wid = tid >> 6;
    int wm = (wid >> 1) * 64;
    int wn = (wid & 1) * 64;
    int q = lane >> 4;

    const bf16* aptr[4];
    #pragma unroll
    for (int mf = 0; mf < 4; ++mf) {
        int R = wm + mf * 16 + (lane & 15);
        int grow = m0 + R; if (grow > cnt - 1) grow = cnt - 1;
        aptr[mf] = H + (size_t)(base + grow) * F_INT + q * 8;
    }

    int k4 = (tid >> 5) * 4;
    int nn = (tid & 31) * 4;
    const float* bsrc = Wd + (size_t)k4 * D_HID + n0 + nn;

    int boff[4];
    #pragma unroll
    for (int nf = 0; nf < 4; ++nf)
        boff[nf] = swz16(wn + nf * 16 + (lane & 15), q * 8);

    f32x4 acc[4][4];
    f32x4 zero = {0.f, 0.f, 0.f, 0.f};
    #pragma unroll
    for (int i = 0; i < 4; ++i)
        #pragma unroll
        for (int j = 0; j < 4; ++j) acc[i][j] = zero;

    bf16x8 af[4];
    float4 rb[4];

    auto LOADAF = [&](int kt) {
        #pragma unroll
        for (int mf = 0; mf < 4; ++mf)
            af[mf] = *(const bf16x8*)(aptr[mf] + kt * 32);
    };
    auto LOADB = [&](int t) {
        const float* b0 = bsrc + (size_t)(t * 32) * D_HID;
        rb[0] = *(const float4*)b0;
        rb[1] = *(const float4*)(b0 + D_HID);
        rb[2] = *(const float4*)(b0 + 2 * D_HID);
        rb[3] = *(const float4*)(b0 + 3 * D_HID);
    };
    auto WRITEB = [&](int s) {
        bf16x4 p0 = {(bf16)rb[0].x, (bf16)rb[1].x, (bf16)rb[2].x, (bf16)rb[3].x};
        bf16x4 p1 = {(bf16)rb[0].y, (bf16)rb[1].y, (bf16)rb[2].y, (bf16)rb[3].y};
        bf16x4 p2 = {(bf16)rb[0].z, (bf16)rb[1].z, (bf16)rb[2].z, (bf16)rb[3].z};
        bf16x4 p3 = {(bf16)rb[0].w, (bf16)rb[1].w, (bf16)rb[2].w, (bf16)rb[3].w};
        *(bf16x4*)&Bs[s][swz16(nn + 0, k4)] = p0;
        *(bf16x4*)&Bs[s][swz16(nn + 1, k4)] = p1;
        *(bf16x4*)&Bs[s][swz16(nn + 2, k4)] = p2;
        *(bf16x4*)&Bs[s][swz16(nn + 3, k4)] = p3;
    };
    auto MM = [&](int cur) {
        #pragma unroll
        for (int nf = 0; nf < 4; ++nf) {
            bf16x8 bfr = *(const bf16x8*)&Bs[cur][boff[nf]];
            #pragma unroll
            for (int mf = 0; mf < 4; ++mf)
                acc[mf][nf] = __builtin_amdgcn_mfma_f32_16x16x32_bf16(af[mf], bfr, acc[mf][nf], 0, 0, 0);
        }
    };

    const int NT = F_INT / 32;   // 44
    LOADB(0);
    WRITEB(0);
    LOADB(1);
    BAR();

    for (int kt = 0; kt < NT; ++kt) {
        int cur = kt & 1, nxt = cur ^ 1;
        LOADAF(kt);
        if (kt + 1 < NT) WRITEB(nxt);
        if (kt + 2 < NT) LOADB(kt + 2);
        MM(cur);
        BAR();
    }

    #pragma unroll
    for (int mf = 0; mf < 4; ++mf) {
        #pragma unroll
        for (int nf = 0; nf < 4; ++nf) {
            int col = n0 + wn + nf * 16 + (lane & 15);
            #pragma unroll
            for (int r = 0; r < 4; ++r) {
                int grow = m0 + wm + mf * 16 + (lane >> 4) * 4 + r;
                if (grow < cnt)
                    P[(size_t)(base + grow) * D_HID + col] = (bf16)acc[mf][nf][r];
            }
        }
    }
}

// ---------------- combine ----------------
__global__ __launch_bounds__(256) void k_combine(const bf16* __restrict__ P,
                                                 const int* __restrict__ slots,
                                                 const float* __restrict__ tok_w,
                                                 float* __restrict__ out) {
    int t = blockIdx.x;
    int tid = threadIdx.x;
    __shared__ int ss[TOPK];
    __shared__ float ww[TOPK];
    if (tid < TOPK) { ss[tid] = slots[t * TOPK + tid]; ww[tid] = tok_w[t * TOPK + tid]; }
    __syncthreads();
    int c0 = tid * 8;
    float acc[8];
    {
        bf16x8 v0 = *(const bf16x8*)(P + (size_t)(SH_BASE + t) * D_HID + c0);
        bf16x8 v1 = *(const bf16x8*)(P + (size_t)(SH_BASE + T_TOK + t) * D_HID + c0);
        #pragma unroll
        for (int i = 0; i < 8; ++i) acc[i] = (float)v0[i] + (float)v1[i];
    }
    #pragma unroll
    for (int k = 0; k < TOPK; ++k) {
        bf16x8 v = *(const bf16x8*)(P + (size_t)ss[k] * D_HID + c0);
        float w = ww[k];
        #pragma unroll
        for (int i = 0; i < 8; ++i) acc[i] += w * (float)v[i];
    }
    float4 o0 = {acc[0], acc[1], acc[2], acc[3]};
    float4 o1 = {acc[4], acc[5], acc[6], acc[7]};
    *(float4*)(out + (size_t)t * D_HID + c0) = o0;
    *(float4*)(out + (size_t)t * D_HID + c0 + 4) = o1;
}

extern "C" void kernel_launch(void* const* d_in, const int* in_sizes, int n_in,
                              void* d_out, int out_size, void* d_ws, size_t ws_size,
                              hipStream_t stream) {
    const float* x  = (const float*)d_in[0];
    const float* wr = (const float*)d_in[1];
    const float* wg = (const float*)d_in[2];
    const float* wu = (const float*)d_in[3];
    const float* wd = (const float*)d_in[4];
    const float* sg = (const float*)d_in[5];
    const float* su = (const float*)d_in[6];
    const float* sd = (const float*)d_in[7];
    float* out = (float*)d_out;

    const size_t H_BYTES  = (size_t)ROWS_TOTAL * F_INT * 2;
    const size_t P_BYTES  = (size_t)ROWS_TOTAL * D_HID * 2;
    const size_t XP_BYTES = (size_t)XP_ROWS * D_HID * 2;

    char* w = (char*)d_ws;
    int*   counts   = (int*)(w + 0);
    int*   cursors  = (int*)(w + 256);
    int*   offs     = (int*)(w + 512);
    int*   tok_e    = (int*)(w + 8192);
    float* tok_w    = (float*)(w + 8192 + 49152);
    int*   slots    = (int*)(w + 8192 + 2 * 49152);
    int*   rowtok   = (int*)(w + 8192 + 3 * 49152);
    bf16*  H        = (bf16*)(w + 262144);
    bf16*  P        = (bf16*)(w + 262144 + H_BYTES);
    bf16*  Xp       = (bf16*)(w + 262144 + H_BYTES + P_BYTES);

    int dense = (ws_size >= 262144 + H_BYTES + P_BYTES + XP_BYTES) ? 1 : 0;

    hipMemsetAsync(counts, 0, 128, stream);
    k_router<<<T_TOK, 256, 0, stream>>>(x, wr, counts, tok_e, tok_w);
    k_plan<<<1, 64, 0, stream>>>(counts, offs, cursors);
    k_assign<<<T_TOK / 256, 256, 0, stream>>>(tok_e, offs, cursors, slots, rowtok);
    if (dense) {
        k_gather<<<XP_ROWS, 256, 0, stream>>>(x, rowtok, Xp);
    } else {
        k_xcvt<<<T_TOK * D_HID / 2048, 256, 0, stream>>>(x, Xp);
    }
    k_gateup<<<MAXT_GU * GU_NBN, 256, 0, stream>>>(
        Xp, wg, wu, sg, su, rowtok, counts, offs, H, dense);
    k_down<<<MAXT_DN * (D_HID / 128), 256, 0, stream>>>(
        H, wd, sd, counts, offs, P);
    k_combine<<<T_TOK, 256, 0, stream>>>(P, slots, tok_w, out);
}

// Round 13
// 758.014 us; speedup vs baseline: 1.3766x; 1.3766x over previous
//
#include <hip/hip_runtime.h>
#include <hip/hip_bf16.h>

#define T_TOK 2048
#define D_HID 2048
#define F_INT 1408
#define N_EXP 32
#define TOPK 6
#define NJOBS 34
#define SH_BASE 12288
#define ROWS_TOTAL 16384
#define XP_ROWS 14336
#define MAXT_GU 159
#define GU_NBN 22
#define MAXT_DN 159
#define LDSW 40                // B LDS row stride (80 B)

typedef __bf16 bf16;
typedef __bf16 bf16x4 __attribute__((ext_vector_type(4)));
typedef __bf16 bf16x8 __attribute__((ext_vector_type(8)));
typedef float f32x4 __attribute__((ext_vector_type(4)));

// counted-vmcnt barrier: retires this phase's 2 gll, keeps 4 B-loads in flight
#define WAITBAR() asm volatile("s_waitcnt vmcnt(4) lgkmcnt(0)\n\ts_barrier" ::: "memory")

__device__ __forceinline__ void gll16(const bf16* g, bf16* l) {
    __builtin_amdgcn_global_load_lds((const __attribute__((address_space(1))) void*)g,
                                     (__attribute__((address_space(3))) void*)l, 16, 0, 0);
}

// B swizzle (R8-verified)
__device__ __forceinline__ int swz16(int r, int k) {
    return r * LDSW + ((((k >> 3) ^ ((r >> 3) & 3) ^ ((r >> 5) & 3)) & 3) << 3) + (k & 7);
}
// A linear-layout slot permutation (frag reads at b128 floor)
__device__ __forceinline__ int aslot(int r) { return (r + (r >> 2)) & 3; }

__device__ __forceinline__ int decode_tile(const int* __restrict__ counts, int bid,
                                           int NBN, int MSH, int NSH,
                                           int& job, int& n0, int& m0) {
    int total = 0;
    for (int j = 0; j < NJOBS; ++j) {
        int c = (j < N_EXP) ? counts[j] : T_TOK;
        total += ((c + (1 << MSH) - 1) >> MSH) * NBN;
    }
    if (bid >= total) return 0;
    int q = total >> 3, r = total & 7, x = bid & 7, o = bid >> 3;
    int L = (x < r ? x * (q + 1) : r * (q + 1) + (x - r) * q) + o;
    int acc = 0;
    for (int j = 0; j < NJOBS; ++j) {
        int c = (j < N_EXP) ? counts[j] : T_TOK;
        int tc = (c + (1 << MSH) - 1) >> MSH;
        int b = tc * NBN;
        if (L < acc + b) {
            int rem = L - acc;
            int n0i = rem / tc;
            job = j;
            n0 = n0i << NSH;
            m0 = (rem - n0i * tc) << MSH;
            return 1;
        }
        acc += b;
    }
    return 0;
}

// ---------------- router ----------------
__global__ __launch_bounds__(256) void k_router(const float* __restrict__ x,
                                                const float* __restrict__ wr,
                                                int* __restrict__ counts,
                                                int* __restrict__ tok_e,
                                                float* __restrict__ tok_w) {
    int t = blockIdx.x;
    int tid = threadIdx.x;
    __shared__ float xs[D_HID];
    __shared__ float part[8][32];
    __shared__ float probs[N_EXP];

    const float4* xsrc = (const float4*)(x + (size_t)t * D_HID);
    float4* xdst = (float4*)xs;
    for (int i = tid; i < D_HID / 4; i += 256) xdst[i] = xsrc[i];
    __syncthreads();

    int e = tid & 31, c = tid >> 5;
    float p = 0.f;
    const float* wp = wr + e;
    #pragma unroll 8
    for (int h = c * 256; h < c * 256 + 256; ++h) p += xs[h] * wp[h * 32];
    part[c][e] = p;
    __syncthreads();

    if (tid < 32) {
        float l = 0.f;
        #pragma unroll
        for (int cc = 0; cc < 8; ++cc) l += part[cc][tid];
        float m = l;
        for (int off = 16; off; off >>= 1) m = fmaxf(m, __shfl_xor(m, off));
        float ex = __expf(l - m);
        float s = ex;
        for (int off = 16; off; off >>= 1) s += __shfl_xor(s, off);
        probs[tid] = ex / s;
    }
    __syncthreads();

    if (tid == 0) {
        unsigned used = 0;
        int ids[TOPK]; float wsv[TOPK]; float wsum = 0.f;
        for (int k = 0; k < TOPK; ++k) {
            int best = 0; float bv = -1.f;
            for (int ee = 0; ee < N_EXP; ++ee)
                if (!((used >> ee) & 1u) && probs[ee] > bv) { bv = probs[ee]; best = ee; }
            used |= 1u << best;
            ids[k] = best; wsv[k] = bv; wsum += bv;
        }
        float inv = 1.f / wsum;
        for (int k = 0; k < TOPK; ++k) {
            tok_e[t * TOPK + k] = ids[k];
            tok_w[t * TOPK + k] = wsv[k] * inv;
            atomicAdd(&counts[ids[k]], 1);
        }
    }
}

// ---------------- plan ----------------
__global__ void k_plan(const int* __restrict__ counts, int* __restrict__ offs,
                       int* __restrict__ cursors) {
    int tid = threadIdx.x;
    if (tid < N_EXP) cursors[tid] = 0;
    if (tid == 0) {
        int o = 0;
        offs[0] = 0;
        for (int e2 = 0; e2 < N_EXP; ++e2) { o += counts[e2]; offs[e2 + 1] = o; }
        offs[33] = offs[32] + T_TOK;
        offs[34] = offs[33] + T_TOK;
    }
}

// ---------------- assign ----------------
__global__ __launch_bounds__(256) void k_assign(const int* __restrict__ tok_e,
                                                const int* __restrict__ offs,
                                                int* __restrict__ cursors,
                                                int* __restrict__ slots,
                                                int* __restrict__ rowtok) {
    int t = blockIdx.x * 256 + threadIdx.x;
    #pragma unroll
    for (int k = 0; k < TOPK; ++k) {
        int e = tok_e[t * TOPK + k];
        int pos = atomicAdd(&cursors[e], 1);
        int slot = offs[e] + pos;
        slots[t * TOPK + k] = slot;
        rowtok[slot] = t;
    }
    rowtok[SH_BASE + t] = t;
    rowtok[SH_BASE + T_TOK + t] = t;
}

// ---------------- gather+cvt ----------------
__global__ __launch_bounds__(256) void k_gather(const float* __restrict__ x,
                                                const int* __restrict__ rowtok,
                                                bf16* __restrict__ Xp) {
    int s = blockIdx.x;
    int src = (s < SH_BASE) ? rowtok[s] : (s - SH_BASE);
    const float* xr = x + (size_t)src * D_HID + threadIdx.x * 8;
    float4 f0 = *(const float4*)xr;
    float4 f1 = *(const float4*)(xr + 4);
    bf16x8 v = {(bf16)f0.x, (bf16)f0.y, (bf16)f0.z, (bf16)f0.w,
                (bf16)f1.x, (bf16)f1.y, (bf16)f1.z, (bf16)f1.w};
    *(bf16x8*)(Xp + (size_t)s * D_HID + threadIdx.x * 8) = v;
}

__global__ __launch_bounds__(256) void k_xcvt(const float* __restrict__ x,
                                              bf16* __restrict__ xb) {
    int i = blockIdx.x * 2048 + threadIdx.x * 8;
    float4 f0 = *(const float4*)(x + i);
    float4 f1 = *(const float4*)(x + i + 4);
    bf16x8 v = {(bf16)f0.x, (bf16)f0.y, (bf16)f0.z, (bf16)f0.w,
                (bf16)f1.x, (bf16)f1.y, (bf16)f1.z, (bf16)f1.w};
    *(bf16x8*)(xb + i) = v;
}

// ---------------- GEMM1: H = silu(X Wg) * (X Wu) ----------------
// BM=128 x BN=64, BK=32, 4 waves. R11 base + (a) 3-deep A gll buffers so the
// consumed A-buf was retired a barrier earlier, (b) register-prefetch of next
// phase's A-frags DURING the MFMA phase (afA/afB alternating, 2-unrolled).
__global__ __launch_bounds__(256, 3) void k_gateup(
    const bf16* __restrict__ xp, const float* __restrict__ wg, const float* __restrict__ wu,
    const float* __restrict__ sg, const float* __restrict__ su,
    const int* __restrict__ rowtok, const int* __restrict__ counts, const int* __restrict__ offs,
    bf16* __restrict__ H, int dense) {

    int job, n0, m0;
    if (!decode_tile(counts, blockIdx.x, GU_NBN, 7, 6, job, n0, m0)) return;
    int cnt = (job < N_EXP) ? counts[job] : T_TOK;
    int base = offs[job];
    const float* Wg = (job < N_EXP) ? wg + (size_t)job * D_HID * F_INT
                                    : sg + (size_t)(job - N_EXP) * D_HID * F_INT;
    const float* Wu = (job < N_EXP) ? wu + (size_t)job * D_HID * F_INT
                                    : su + (size_t)(job - N_EXP) * D_HID * F_INT;

    __shared__ bf16 As[3][128 * 32];         // linear gll dest, 3 x 8 KB
    __shared__ bf16 Bg[2][64 * LDSW];        // 10 KB
    __shared__ bf16 Bu[2][64 * LDSW];        // 10 KB

    int tid = threadIdx.x;
    int lane = tid & 63;
    int wid = tid >> 6;
    int wm = (wid & 1) * 64;
    int wn = (wid >> 1) * 32;

    // per-lane gll A sources (2 instrs/wave: 16 rows each)
    const bf16* agsrc[2];
    #pragma unroll
    for (int i = 0; i < 2; ++i) {
        int rl = wid * 32 + i * 16 + (lane >> 2);
        int grow = m0 + rl; if (grow > cnt - 1) grow = cnt - 1;
        int arow = dense ? (((job < N_EXP) ? base : SH_BASE) + grow)
                         : rowtok[base + grow];
        int kslot = (lane & 3) ^ aslot(rl);
        agsrc[i] = xp + (size_t)arow * D_HID + kslot * 8;
    }

    // B staging: half threads Wg / half Wu; n-fastest coalesced
    int sub = tid & 127;
    int nn = (sub & 15) * 4;
    int k4 = (sub >> 4) * 4;
    const float* wsrc = ((tid & 128) ? Wu : Wg) + (size_t)k4 * F_INT + n0 + nn;

    // loop-invariant fragment offsets
    int q = lane >> 4;
    int aoff[4], boff[2];
    #pragma unroll
    for (int mf = 0; mf < 4; ++mf) {
        int R = wm + mf * 16 + (lane & 15);
        aoff[mf] = R * 32 + ((q ^ aslot(R)) << 3);
    }
    #pragma unroll
    for (int nf = 0; nf < 2; ++nf)
        boff[nf] = swz16(wn + nf * 16 + (lane & 15), q * 8);

    f32x4 accg[4][2], accu[4][2];
    f32x4 zero = {0.f, 0.f, 0.f, 0.f};
    #pragma unroll
    for (int i = 0; i < 4; ++i)
        #pragma unroll
        for (int j = 0; j < 2; ++j) { accg[i][j] = zero; accu[i][j] = zero; }

    bf16x8 afA[4], afB[4];
    float4 rb[4];

    auto GLLA = [&](int b, int t) {
        gll16(agsrc[0] + t * 32, &As[b][wid * 1024]);
        gll16(agsrc[1] + t * 32, &As[b][wid * 1024 + 512]);
    };
    auto LOADB = [&](int t) {
        const float* b0 = wsrc + (size_t)(t * 32) * F_INT;
        rb[0] = *(const float4*)b0;
        rb[1] = *(const float4*)(b0 + F_INT);
        rb[2] = *(const float4*)(b0 + 2 * F_INT);
        rb[3] = *(const float4*)(b0 + 3 * F_INT);
    };
    auto WRITEB = [&](int s) {
        bf16* bd = (tid & 128) ? Bu[s] : Bg[s];
        bf16x4 p0 = {(bf16)rb[0].x, (bf16)rb[1].x, (bf16)rb[2].x, (bf16)rb[3].x};
        bf16x4 p1 = {(bf16)rb[0].y, (bf16)rb[1].y, (bf16)rb[2].y, (bf16)rb[3].y};
        bf16x4 p2 = {(bf16)rb[0].z, (bf16)rb[1].z, (bf16)rb[2].z, (bf16)rb[3].z};
        bf16x4 p3 = {(bf16)rb[0].w, (bf16)rb[1].w, (bf16)rb[2].w, (bf16)rb[3].w};
        *(bf16x4*)&bd[swz16(nn + 0, k4)] = p0;
        *(bf16x4*)&bd[swz16(nn + 1, k4)] = p1;
        *(bf16x4*)&bd[swz16(nn + 2, k4)] = p2;
        *(bf16x4*)&bd[swz16(nn + 3, k4)] = p3;
    };
    auto PREF = [&](bf16x8 (&dst)[4], int b) {
        const bf16* ab = &As[b][0];
        #pragma unroll
        for (int mf = 0; mf < 4; ++mf)
            dst[mf] = *(const bf16x8*)&ab[aoff[mf]];
    };
    auto MM = [&](const bf16x8 (&af)[4], int cur) {
        #pragma unroll
        for (int nf = 0; nf < 2; ++nf) {
            bf16x8 bfr = *(const bf16x8*)&Bg[cur][boff[nf]];
            bf16x8 ufr = *(const bf16x8*)&Bu[cur][boff[nf]];
            #pragma unroll
            for (int mf = 0; mf < 4; ++mf) {
                accg[mf][nf] = __builtin_amdgcn_mfma_f32_16x16x32_bf16(af[mf], bfr, accg[mf][nf], 0, 0, 0);
                accu[mf][nf] = __builtin_amdgcn_mfma_f32_16x16x32_bf16(af[mf], ufr, accu[mf][nf], 0, 0, 0);
            }
        }
    };

    const int NT = D_HID / 32;   // 64 (even)
    // prologue: fill A0 (tile0), A1 (tile1); B0 (tile0); rb <- tile1
    GLLA(0, 0);
    GLLA(1, 1);
    __builtin_amdgcn_sched_barrier(0);
    LOADB(0);
    WRITEB(0);                       // implicit vmcnt drains gll A0/A1 + B loads
    LOADB(1);
    asm volatile("s_waitcnt lgkmcnt(0)\n\ts_barrier" ::: "memory");
    PREF(afA, 0);                    // A tile0 frags (post-barrier, prologue only)

    for (int kt = 0; kt < NT; kt += 2) {
        // even phase: MM(afA, B0); prefetch afB <- A[(kt+1)%3]
        {
            int tg = kt + 2 < NT ? kt + 2 : NT - 1;
            GLLA((kt + 2) % 3, tg);
            __builtin_amdgcn_sched_barrier(0);   // keep gll older than LOADB in FIFO
            WRITEB(1);                           // tile kt+1 (rb)
            LOADB(tg);                           // rb <- tile kt+2
            PREF(afB, (kt + 1) % 3);             // overlaps MM
            MM(afA, 0);
            WAITBAR();                           // vmcnt(4): retire this phase's gll
        }
        // odd phase: MM(afB, B1); prefetch afA <- A[(kt+2)%3]
        {
            int tg = kt + 3 < NT ? kt + 3 : NT - 1;
            GLLA((kt + 3) % 3, tg);
            __builtin_amdgcn_sched_barrier(0);
            WRITEB(0);                           // tile kt+2 (rb)
            LOADB(tg);                           // rb <- tile kt+3
            PREF(afA, (kt + 2) % 3);
            MM(afB, 1);
            WAITBAR();
        }
    }

    // epilogue: h = silu(g) * u
    #pragma unroll
    for (int mf = 0; mf < 4; ++mf) {
        #pragma unroll
        for (int nf = 0; nf < 2; ++nf) {
            int col = n0 + wn + nf * 16 + (lane & 15);
            #pragma unroll
            for (int r = 0; r < 4; ++r) {
                int grow = m0 + wm + mf * 16 + (lane >> 4) * 4 + r;
                if (grow < cnt) {
                    float g = accg[mf][nf][r];
                    float u = accu[mf][nf][r];
                    float h = g * u / (1.f + __expf(-g));
                    H[(size_t)(base + grow) * F_INT + col] = (bf16)h;
                }
            }
        }
    }
}

// ---------------- GEMM2: P = H Wd (unchanged R11 structure) ----------------
__global__ __launch_bounds__(256, 4) void k_down(
    const bf16* __restrict__ H, const float* __restrict__ wd, const float* __restrict__ sd,
    const int* __restrict__ counts, const int* __restrict__ offs,
    bf16* __restrict__ P) {

    int job, n0, m0;
    if (!decode_tile(counts, blockIdx.x, D_HID / 128, 7, 7, job, n0, m0)) return;
    int cnt = (job < N_EXP) ? counts[job] : T_TOK;
    int base = offs[job];
    const float* Wd = (job < N_EXP) ? wd + (size_t)job * F_INT * D_HID
                                    : sd + (size_t)(job - N_EXP) * F_INT * D_HID;

    __shared__ bf16 As[2][128 * 32];
    __shared__ bf16 Bs[2][128 * LDSW];

    int tid = threadIdx.x;
    int lane = tid & 63;
    int wid = tid >> 6;
    int wm = (wid >> 1) * 64;
    int wn = (wid & 1) * 64;

    const bf16* agsrc[2];
    #pragma unroll
    for (int i = 0; i < 2; ++i) {
        int rl = wid * 32 + i * 16 + (lane >> 2);
        int grow = m0 + rl; if (grow > cnt - 1) grow = cnt - 1;
        int kslot = (lane & 3) ^ aslot(rl);
        agsrc[i] = H + (size_t)(base + grow) * F_INT + kslot * 8;
    }

    int k4 = (tid >> 5) * 4;
    int nn = (tid & 31) * 4;
    const float* bsrc = Wd + (size_t)k4 * D_HID + n0 + nn;

    int q = lane >> 4;
    int aoff[4], boff[4];
    #pragma unroll
    for (int mf = 0; mf < 4; ++mf) {
        int R = wm + mf * 16 + (lane & 15);
        aoff[mf] = R * 32 + ((q ^ aslot(R)) << 3);
    }
    #pragma unroll
    for (int nf = 0; nf < 4; ++nf)
        boff[nf] = swz16(wn + nf * 16 + (lane & 15), q * 8);

    f32x4 acc[4][4];
    f32x4 zero = {0.f, 0.f, 0.f, 0.f};
    #pragma unroll
    for (int i = 0; i < 4; ++i)
        #pragma unroll
        for (int j = 0; j < 4; ++j) acc[i][j] = zero;

    float4 rb[4];

    auto GLLA = [&](int s, int t) {
        gll16(agsrc[0] + t * 32, &As[s][wid * 1024]);
        gll16(agsrc[1] + t * 32, &As[s][wid * 1024 + 512]);
    };
    auto LOADB = [&](int t) {
        const float* b0 = bsrc + (size_t)(t * 32) * D_HID;
        rb[0] = *(const float4*)b0;
        rb[1] = *(const float4*)(b0 + D_HID);
        rb[2] = *(const float4*)(b0 + 2 * D_HID);
        rb[3] = *(const float4*)(b0 + 3 * D_HID);
    };
    auto WRITEB = [&](int s) {
        bf16x4 p0 = {(bf16)rb[0].x, (bf16)rb[1].x, (bf16)rb[2].x, (bf16)rb[3].x};
        bf16x4 p1 = {(bf16)rb[0].y, (bf16)rb[1].y, (bf16)rb[2].y, (bf16)rb[3].y};
        bf16x4 p2 = {(bf16)rb[0].z, (bf16)rb[1].z, (bf16)rb[2].z, (bf16)rb[3].z};
        bf16x4 p3 = {(bf16)rb[0].w, (bf16)rb[1].w, (bf16)rb[2].w, (bf16)rb[3].w};
        *(bf16x4*)&Bs[s][swz16(nn + 0, k4)] = p0;
        *(bf16x4*)&Bs[s][swz16(nn + 1, k4)] = p1;
        *(bf16x4*)&Bs[s][swz16(nn + 2, k4)] = p2;
        *(bf16x4*)&Bs[s][swz16(nn + 3, k4)] = p3;
    };
    auto MM = [&](int cur) {
        bf16x8 af[4];
        #pragma unroll
        for (int mf = 0; mf < 4; ++mf)
            af[mf] = *(const bf16x8*)&As[cur][aoff[mf]];
        #pragma unroll
        for (int nf = 0; nf < 4; ++nf) {
            bf16x8 bfr = *(const bf16x8*)&Bs[cur][boff[nf]];
            #pragma unroll
            for (int mf = 0; mf < 4; ++mf)
                acc[mf][nf] = __builtin_amdgcn_mfma_f32_16x16x32_bf16(af[mf], bfr, acc[mf][nf], 0, 0, 0);
        }
    };

    const int NT = F_INT / 32;   // 44
    GLLA(0, 0);
    __builtin_amdgcn_sched_barrier(0);
    LOADB(0);
    WRITEB(0);
    LOADB(1);
    asm volatile("s_waitcnt vmcnt(4) lgkmcnt(0)\n\ts_barrier" ::: "memory");

    for (int kt = 0; kt < NT; ++kt) {
        int cur = kt & 1, nxt = cur ^ 1;
        int t1 = kt + 1 < NT ? kt + 1 : NT - 1;
        int t2 = kt + 2 < NT ? kt + 2 : NT - 1;
        GLLA(nxt, t1);
        __builtin_amdgcn_sched_barrier(0);
        WRITEB(nxt);
        LOADB(t2);
        MM(cur);
        asm volatile("s_waitcnt vmcnt(4) lgkmcnt(0)\n\ts_barrier" ::: "memory");
    }

    #pragma unroll
    for (int mf = 0; mf < 4; ++mf) {
        #pragma unroll
        for (int nf = 0; nf < 4; ++nf) {
            int col = n0 + wn + nf * 16 + (lane & 15);
            #pragma unroll
            for (int r = 0; r < 4; ++r) {
                int grow = m0 + wm + mf * 16 + (lane >> 4) * 4 + r;
                if (grow < cnt)
                    P[(size_t)(base + grow) * D_HID + col] = (bf16)acc[mf][nf][r];
            }
        }
    }
}

// ---------------- combine ----------------
__global__ __launch_bounds__(256) void k_combine(const bf16* __restrict__ P,
                                                 const int* __restrict__ slots,
                                                 const float* __restrict__ tok_w,
                                                 float* __restrict__ out) {
    int t = blockIdx.x;
    int tid = threadIdx.x;
    __shared__ int ss[TOPK];
    __shared__ float ww[TOPK];
    if (tid < TOPK) { ss[tid] = slots[t * TOPK + tid]; ww[tid] = tok_w[t * TOPK + tid]; }
    __syncthreads();
    int c0 = tid * 8;
    float acc[8];
    {
        bf16x8 v0 = *(const bf16x8*)(P + (size_t)(SH_BASE + t) * D_HID + c0);
        bf16x8 v1 = *(const bf16x8*)(P + (size_t)(SH_BASE + T_TOK + t) * D_HID + c0);
        #pragma unroll
        for (int i = 0; i < 8; ++i) acc[i] = (float)v0[i] + (float)v1[i];
    }
    #pragma unroll
    for (int k = 0; k < TOPK; ++k) {
        bf16x8 v = *(const bf16x8*)(P + (size_t)ss[k] * D_HID + c0);
        float w = ww[k];
        #pragma unroll
        for (int i = 0; i < 8; ++i) acc[i] += w * (float)v[i];
    }
    float4 o0 = {acc[0], acc[1], acc[2], acc[3]};
    float4 o1 = {acc[4], acc[5], acc[6], acc[7]};
    *(float4*)(out + (size_t)t * D_HID + c0) = o0;
    *(float4*)(out + (size_t)t * D_HID + c0 + 4) = o1;
}

extern "C" void kernel_launch(void* const* d_in, const int* in_sizes, int n_in,
                              void* d_out, int out_size, void* d_ws, size_t ws_size,
                              hipStream_t stream) {
    const float* x  = (const float*)d_in[0];
    const float* wr = (const float*)d_in[1];
    const float* wg = (const float*)d_in[2];
    const float* wu = (const float*)d_in[3];
    const float* wd = (const float*)d_in[4];
    const float* sg = (const float*)d_in[5];
    const float* su = (const float*)d_in[6];
    const float* sd = (const float*)d_in[7];
    float* out = (float*)d_out;

    const size_t H_BYTES  = (size_t)ROWS_TOTAL * F_INT * 2;
    const size_t P_BYTES  = (size_t)ROWS_TOTAL * D_HID * 2;
    const size_t XP_BYTES = (size_t)XP_ROWS * D_HID * 2;

    char* w = (char*)d_ws;
    int*   counts   = (int*)(w + 0);
    int*   cursors  = (int*)(w + 256);
    int*   offs     = (int*)(w + 512);
    int*   tok_e    = (int*)(w + 8192);
    float* tok_w    = (float*)(w + 8192 + 49152);
    int*   slots    = (int*)(w + 8192 + 2 * 49152);
    int*   rowtok   = (int*)(w + 8192 + 3 * 49152);
    bf16*  H        = (bf16*)(w + 262144);
    bf16*  P        = (bf16*)(w + 262144 + H_BYTES);
    bf16*  Xp       = (bf16*)(w + 262144 + H_BYTES + P_BYTES);

    int dense = (ws_size >= 262144 + H_BYTES + P_BYTES + XP_BYTES) ? 1 : 0;

    hipMemsetAsync(counts, 0, 128, stream);
    k_router<<<T_TOK, 256, 0, stream>>>(x, wr, counts, tok_e, tok_w);
    k_plan<<<1, 64, 0, stream>>>(counts, offs, cursors);
    k_assign<<<T_TOK / 256, 256, 0, stream>>>(tok_e, offs, cursors, slots, rowtok);
    if (dense) {
        k_gather<<<XP_ROWS, 256, 0, stream>>>(x, rowtok, Xp);
    } else {
        k_xcvt<<<T_TOK * D_HID / 2048, 256, 0, stream>>>(x, Xp);
    }
    k_gateup<<<MAXT_GU * GU_NBN, 256, 0, stream>>>(
        Xp, wg, wu, sg, su, rowtok, counts, offs, H, dense);
    k_down<<<MAXT_DN * (D_HID / 128), 256, 0, stream>>>(
        H, wd, sd, counts, offs, P);
    k_combine<<<T_TOK, 256, 0, stream>>>(P, slots, tok_w, out);
}

// Round 14
// 753.417 us; speedup vs baseline: 1.3850x; 1.0061x over previous
//
#include <hip/hip_runtime.h>
#include <hip/hip_bf16.h>

#define T_TOK 2048
#define D_HID 2048
#define F_INT 1408
#define N_EXP 32
#define TOPK 6
#define NJOBS 34
#define SH_BASE 12288
#define ROWS_TOTAL 16384
#define XP_ROWS 14336
#define MAXT_GU 159
#define GU_NBN 22
#define MAXT_DN 159
#define LDSW 40                // B LDS row stride (80 B)

typedef __bf16 bf16;
typedef __bf16 bf16x4 __attribute__((ext_vector_type(4)));
typedef __bf16 bf16x8 __attribute__((ext_vector_type(8)));
typedef float f32x16 __attribute__((ext_vector_type(16)));

// counted-vmcnt barrier: retires this phase's 2 gll, keeps 4 B-loads in flight
#define WAITBAR() asm volatile("s_waitcnt vmcnt(4) lgkmcnt(0)\n\ts_barrier" ::: "memory")

__device__ __forceinline__ void gll16(const bf16* g, bf16* l) {
    __builtin_amdgcn_global_load_lds((const __attribute__((address_space(1))) void*)g,
                                     (__attribute__((address_space(3))) void*)l, 16, 0, 0);
}

// B swizzle (R8-verified)
__device__ __forceinline__ int swz16(int r, int k) {
    return r * LDSW + ((((k >> 3) ^ ((r >> 3) & 3) ^ ((r >> 5) & 3)) & 3) << 3) + (k & 7);
}
// A linear-layout slot permutation (frag reads <=2-way: r vs r+16 alias only)
__device__ __forceinline__ int aslot(int r) { return (r + (r >> 2)) & 3; }

__device__ __forceinline__ int decode_tile(const int* __restrict__ counts, int bid,
                                           int NBN, int MSH, int NSH,
                                           int& job, int& n0, int& m0) {
    int total = 0;
    for (int j = 0; j < NJOBS; ++j) {
        int c = (j < N_EXP) ? counts[j] : T_TOK;
        total += ((c + (1 << MSH) - 1) >> MSH) * NBN;
    }
    if (bid >= total) return 0;
    int q = total >> 3, r = total & 7, x = bid & 7, o = bid >> 3;
    int L = (x < r ? x * (q + 1) : r * (q + 1) + (x - r) * q) + o;
    int acc = 0;
    for (int j = 0; j < NJOBS; ++j) {
        int c = (j < N_EXP) ? counts[j] : T_TOK;
        int tc = (c + (1 << MSH) - 1) >> MSH;
        int b = tc * NBN;
        if (L < acc + b) {
            int rem = L - acc;
            int n0i = rem / tc;
            job = j;
            n0 = n0i << NSH;
            m0 = (rem - n0i * tc) << MSH;
            return 1;
        }
        acc += b;
    }
    return 0;
}

// ---------------- router ----------------
__global__ __launch_bounds__(256) void k_router(const float* __restrict__ x,
                                                const float* __restrict__ wr,
                                                int* __restrict__ counts,
                                                int* __restrict__ tok_e,
                                                float* __restrict__ tok_w) {
    int t = blockIdx.x;
    int tid = threadIdx.x;
    __shared__ float xs[D_HID];
    __shared__ float part[8][32];
    __shared__ float probs[N_EXP];

    const float4* xsrc = (const float4*)(x + (size_t)t * D_HID);
    float4* xdst = (float4*)xs;
    for (int i = tid; i < D_HID / 4; i += 256) xdst[i] = xsrc[i];
    __syncthreads();

    int e = tid & 31, c = tid >> 5;
    float p = 0.f;
    const float* wp = wr + e;
    #pragma unroll 8
    for (int h = c * 256; h < c * 256 + 256; ++h) p += xs[h] * wp[h * 32];
    part[c][e] = p;
    __syncthreads();

    if (tid < 32) {
        float l = 0.f;
        #pragma unroll
        for (int cc = 0; cc < 8; ++cc) l += part[cc][tid];
        float m = l;
        for (int off = 16; off; off >>= 1) m = fmaxf(m, __shfl_xor(m, off));
        float ex = __expf(l - m);
        float s = ex;
        for (int off = 16; off; off >>= 1) s += __shfl_xor(s, off);
        probs[tid] = ex / s;
    }
    __syncthreads();

    if (tid == 0) {
        unsigned used = 0;
        int ids[TOPK]; float wsv[TOPK]; float wsum = 0.f;
        for (int k = 0; k < TOPK; ++k) {
            int best = 0; float bv = -1.f;
            for (int ee = 0; ee < N_EXP; ++ee)
                if (!((used >> ee) & 1u) && probs[ee] > bv) { bv = probs[ee]; best = ee; }
            used |= 1u << best;
            ids[k] = best; wsv[k] = bv; wsum += bv;
        }
        float inv = 1.f / wsum;
        for (int k = 0; k < TOPK; ++k) {
            tok_e[t * TOPK + k] = ids[k];
            tok_w[t * TOPK + k] = wsv[k] * inv;
            atomicAdd(&counts[ids[k]], 1);
        }
    }
}

// ---------------- plan ----------------
__global__ void k_plan(const int* __restrict__ counts, int* __restrict__ offs,
                       int* __restrict__ cursors) {
    int tid = threadIdx.x;
    if (tid < N_EXP) cursors[tid] = 0;
    if (tid == 0) {
        int o = 0;
        offs[0] = 0;
        for (int e2 = 0; e2 < N_EXP; ++e2) { o += counts[e2]; offs[e2 + 1] = o; }
        offs[33] = offs[32] + T_TOK;
        offs[34] = offs[33] + T_TOK;
    }
}

// ---------------- assign ----------------
__global__ __launch_bounds__(256) void k_assign(const int* __restrict__ tok_e,
                                                const int* __restrict__ offs,
                                                int* __restrict__ cursors,
                                                int* __restrict__ slots,
                                                int* __restrict__ rowtok) {
    int t = blockIdx.x * 256 + threadIdx.x;
    #pragma unroll
    for (int k = 0; k < TOPK; ++k) {
        int e = tok_e[t * TOPK + k];
        int pos = atomicAdd(&cursors[e], 1);
        int slot = offs[e] + pos;
        slots[t * TOPK + k] = slot;
        rowtok[slot] = t;
    }
    rowtok[SH_BASE + t] = t;
    rowtok[SH_BASE + T_TOK + t] = t;
}

// ---------------- gather+cvt ----------------
__global__ __launch_bounds__(256) void k_gather(const float* __restrict__ x,
                                                const int* __restrict__ rowtok,
                                                bf16* __restrict__ Xp) {
    int s = blockIdx.x;
    int src = (s < SH_BASE) ? rowtok[s] : (s - SH_BASE);
    const float* xr = x + (size_t)src * D_HID + threadIdx.x * 8;
    float4 f0 = *(const float4*)xr;
    float4 f1 = *(const float4*)(xr + 4);
    bf16x8 v = {(bf16)f0.x, (bf16)f0.y, (bf16)f0.z, (bf16)f0.w,
                (bf16)f1.x, (bf16)f1.y, (bf16)f1.z, (bf16)f1.w};
    *(bf16x8*)(Xp + (size_t)s * D_HID + threadIdx.x * 8) = v;
}

__global__ __launch_bounds__(256) void k_xcvt(const float* __restrict__ x,
                                              bf16* __restrict__ xb) {
    int i = blockIdx.x * 2048 + threadIdx.x * 8;
    float4 f0 = *(const float4*)(x + i);
    float4 f1 = *(const float4*)(x + i + 4);
    bf16x8 v = {(bf16)f0.x, (bf16)f0.y, (bf16)f0.z, (bf16)f0.w,
                (bf16)f1.x, (bf16)f1.y, (bf16)f1.z, (bf16)f1.w};
    *(bf16x8*)(xb + i) = v;
}

// ---------------- GEMM1: H = silu(X Wg) * (X Wu) ----------------
// R11 structure (gll A + counted vmcnt), MFMA switched to 32x32x16:
// 8 MFMA/iter (was 16) at the higher 32x32 rate; same LDS bytes; setprio(T5).
// Wave tile 64x32 of both mats: accg[2]+accu[2] f32x16 = 64 acc regs.
__global__ __launch_bounds__(256, 4) void k_gateup(
    const bf16* __restrict__ xp, const float* __restrict__ wg, const float* __restrict__ wu,
    const float* __restrict__ sg, const float* __restrict__ su,
    const int* __restrict__ rowtok, const int* __restrict__ counts, const int* __restrict__ offs,
    bf16* __restrict__ H, int dense) {

    int job, n0, m0;
    if (!decode_tile(counts, blockIdx.x, GU_NBN, 7, 6, job, n0, m0)) return;
    int cnt = (job < N_EXP) ? counts[job] : T_TOK;
    int base = offs[job];
    const float* Wg = (job < N_EXP) ? wg + (size_t)job * D_HID * F_INT
                                    : sg + (size_t)(job - N_EXP) * D_HID * F_INT;
    const float* Wu = (job < N_EXP) ? wu + (size_t)job * D_HID * F_INT
                                    : su + (size_t)(job - N_EXP) * D_HID * F_INT;

    __shared__ bf16 As[2][128 * 32];         // linear gll dest, 16 KB
    __shared__ bf16 Bg[2][64 * LDSW];        // 10 KB
    __shared__ bf16 Bu[2][64 * LDSW];        // 10 KB

    int tid = threadIdx.x;
    int lane = tid & 63;
    int wid = tid >> 6;
    int wm = (wid & 1) * 64;
    int wn = (wid >> 1) * 32;

    // per-lane gll A sources (2 instrs/wave: 16 rows each)
    const bf16* agsrc[2];
    #pragma unroll
    for (int i = 0; i < 2; ++i) {
        int rl = wid * 32 + i * 16 + (lane >> 2);
        int grow = m0 + rl; if (grow > cnt - 1) grow = cnt - 1;
        int arow = dense ? (((job < N_EXP) ? base : SH_BASE) + grow)
                         : rowtok[base + grow];
        int kslot = (lane & 3) ^ aslot(rl);
        agsrc[i] = xp + (size_t)arow * D_HID + kslot * 8;
    }

    // B staging: half threads Wg / half Wu; n-fastest coalesced
    int sub = tid & 127;
    int nn = (sub & 15) * 4;
    int k4 = (sub >> 4) * 4;
    const float* wsrc = ((tid & 128) ? Wu : Wg) + (size_t)k4 * F_INT + n0 + nn;

    // 32x32x16 fragment offsets: A row=lane&31, kg=(lane>>5); B col=lane&31
    int hk = lane >> 5;                      // 0/1: k-granule half
    int aoff[2][2], boff[2];
    #pragma unroll
    for (int mf = 0; mf < 2; ++mf) {
        int R = wm + mf * 32 + (lane & 31);
        #pragma unroll
        for (int ks = 0; ks < 2; ++ks)
            aoff[mf][ks] = R * 32 + (((ks * 2 + hk) ^ aslot(R)) << 3);
    }
    #pragma unroll
    for (int ks = 0; ks < 2; ++ks)
        boff[ks] = swz16(wn + (lane & 31), (ks * 2 + hk) * 8);

    f32x16 accg[2], accu[2];
    #pragma unroll
    for (int i = 0; i < 2; ++i) { accg[i] = (f32x16)0.f; accu[i] = (f32x16)0.f; }

    float4 rb[4];

    auto GLLA = [&](int s, int t) {
        gll16(agsrc[0] + t * 32, &As[s][wid * 1024]);
        gll16(agsrc[1] + t * 32, &As[s][wid * 1024 + 512]);
    };
    auto LOADB = [&](int t) {
        const float* b0 = wsrc + (size_t)(t * 32) * F_INT;
        rb[0] = *(const float4*)b0;
        rb[1] = *(const float4*)(b0 + F_INT);
        rb[2] = *(const float4*)(b0 + 2 * F_INT);
        rb[3] = *(const float4*)(b0 + 3 * F_INT);
    };
    auto WRITEB = [&](int s) {
        bf16* bd = (tid & 128) ? Bu[s] : Bg[s];
        bf16x4 p0 = {(bf16)rb[0].x, (bf16)rb[1].x, (bf16)rb[2].x, (bf16)rb[3].x};
        bf16x4 p1 = {(bf16)rb[0].y, (bf16)rb[1].y, (bf16)rb[2].y, (bf16)rb[3].y};
        bf16x4 p2 = {(bf16)rb[0].z, (bf16)rb[1].z, (bf16)rb[2].z, (bf16)rb[3].z};
        bf16x4 p3 = {(bf16)rb[0].w, (bf16)rb[1].w, (bf16)rb[2].w, (bf16)rb[3].w};
        *(bf16x4*)&bd[swz16(nn + 0, k4)] = p0;
        *(bf16x4*)&bd[swz16(nn + 1, k4)] = p1;
        *(bf16x4*)&bd[swz16(nn + 2, k4)] = p2;
        *(bf16x4*)&bd[swz16(nn + 3, k4)] = p3;
    };
    auto MM = [&](int cur) {
        __builtin_amdgcn_s_setprio(1);
        #pragma unroll
        for (int ks = 0; ks < 2; ++ks) {
            bf16x8 a0 = *(const bf16x8*)&As[cur][aoff[0][ks]];
            bf16x8 a1 = *(const bf16x8*)&As[cur][aoff[1][ks]];
            bf16x8 bfr = *(const bf16x8*)&Bg[cur][boff[ks]];
            bf16x8 ufr = *(const bf16x8*)&Bu[cur][boff[ks]];
            accg[0] = __builtin_amdgcn_mfma_f32_32x32x16_bf16(a0, bfr, accg[0], 0, 0, 0);
            accg[1] = __builtin_amdgcn_mfma_f32_32x32x16_bf16(a1, bfr, accg[1], 0, 0, 0);
            accu[0] = __builtin_amdgcn_mfma_f32_32x32x16_bf16(a0, ufr, accu[0], 0, 0, 0);
            accu[1] = __builtin_amdgcn_mfma_f32_32x32x16_bf16(a1, ufr, accu[1], 0, 0, 0);
        }
        __builtin_amdgcn_s_setprio(0);
    };

    const int NT = D_HID / 32;   // 64
    GLLA(0, 0);
    __builtin_amdgcn_sched_barrier(0);
    LOADB(0);
    WRITEB(0);
    LOADB(1);
    WAITBAR();

    for (int kt = 0; kt < NT; ++kt) {
        int cur = kt & 1, nxt = cur ^ 1;
        int t1 = kt + 1 < NT ? kt + 1 : NT - 1;
        int t2 = kt + 2 < NT ? kt + 2 : NT - 1;
        GLLA(nxt, t1);
        __builtin_amdgcn_sched_barrier(0);      // keep gll older than LOADB in FIFO
        WRITEB(nxt);
        LOADB(t2);
        MM(cur);
        WAITBAR();
    }

    // epilogue: h = silu(g) * u   (32x32 C/D: col=lane&31, row=(r&3)+8*(r>>2)+4*hk)
    int colg = n0 + wn + (lane & 31);
    #pragma unroll
    for (int mf = 0; mf < 2; ++mf) {
        #pragma unroll
        for (int r = 0; r < 16; ++r) {
            int row = (r & 3) + 8 * (r >> 2) + 4 * hk;
            int grow = m0 + wm + mf * 32 + row;
            if (grow < cnt) {
                float g = accg[mf][r];
                float u = accu[mf][r];
                float h = g * u / (1.f + __expf(-g));
                H[(size_t)(base + grow) * F_INT + colg] = (bf16)h;
            }
        }
    }
}

// ---------------- GEMM2: P = H Wd ----------------
// R11 structure, 32x32x16 MFMA. Wave 64x64: acc[2][2] f32x16 = 64 regs.
__global__ __launch_bounds__(256, 4) void k_down(
    const bf16* __restrict__ H, const float* __restrict__ wd, const float* __restrict__ sd,
    const int* __restrict__ counts, const int* __restrict__ offs,
    bf16* __restrict__ P) {

    int job, n0, m0;
    if (!decode_tile(counts, blockIdx.x, D_HID / 128, 7, 7, job, n0, m0)) return;
    int cnt = (job < N_EXP) ? counts[job] : T_TOK;
    int base = offs[job];
    const float* Wd = (job < N_EXP) ? wd + (size_t)job * F_INT * D_HID
                                    : sd + (size_t)(job - N_EXP) * F_INT * D_HID;

    __shared__ bf16 As[2][128 * 32];
    __shared__ bf16 Bs[2][128 * LDSW];

    int tid = threadIdx.x;
    int lane = tid & 63;
    int wid = tid >> 6;
    int wm = (wid >> 1) * 64;
    int wn = (wid & 1) * 64;
    int hk = lane >> 5;

    const bf16* agsrc[2];
    #pragma unroll
    for (int i = 0; i < 2; ++i) {
        int rl = wid * 32 + i * 16 + (lane >> 2);
        int grow = m0 + rl; if (grow > cnt - 1) grow = cnt - 1;
        int kslot = (lane & 3) ^ aslot(rl);
        agsrc[i] = H + (size_t)(base + grow) * F_INT + kslot * 8;
    }

    int k4 = (tid >> 5) * 4;
    int nn = (tid & 31) * 4;
    const float* bsrc = Wd + (size_t)k4 * D_HID + n0 + nn;

    int aoff[2][2], boff[2][2];
    #pragma unroll
    for (int mf = 0; mf < 2; ++mf) {
        int R = wm + mf * 32 + (lane & 31);
        #pragma unroll
        for (int ks = 0; ks < 2; ++ks)
            aoff[mf][ks] = R * 32 + (((ks * 2 + hk) ^ aslot(R)) << 3);
    }
    #pragma unroll
    for (int nf = 0; nf < 2; ++nf) {
        int C = wn + nf * 32 + (lane & 31);
        #pragma unroll
        for (int ks = 0; ks < 2; ++ks)
            boff[nf][ks] = swz16(C, (ks * 2 + hk) * 8);
    }

    f32x16 acc[2][2];
    #pragma unroll
    for (int i = 0; i < 2; ++i)
        #pragma unroll
        for (int j = 0; j < 2; ++j) acc[i][j] = (f32x16)0.f;

    float4 rb[4];

    auto GLLA = [&](int s, int t) {
        gll16(agsrc[0] + t * 32, &As[s][wid * 1024]);
        gll16(agsrc[1] + t * 32, &As[s][wid * 1024 + 512]);
    };
    auto LOADB = [&](int t) {
        const float* b0 = bsrc + (size_t)(t * 32) * D_HID;
        rb[0] = *(const float4*)b0;
        rb[1] = *(const float4*)(b0 + D_HID);
        rb[2] = *(const float4*)(b0 + 2 * D_HID);
        rb[3] = *(const float4*)(b0 + 3 * D_HID);
    };
    auto WRITEB = [&](int s) {
        bf16x4 p0 = {(bf16)rb[0].x, (bf16)rb[1].x, (bf16)rb[2].x, (bf16)rb[3].x};
        bf16x4 p1 = {(bf16)rb[0].y, (bf16)rb[1].y, (bf16)rb[2].y, (bf16)rb[3].y};
        bf16x4 p2 = {(bf16)rb[0].z, (bf16)rb[1].z, (bf16)rb[2].z, (bf16)rb[3].z};
        bf16x4 p3 = {(bf16)rb[0].w, (bf16)rb[1].w, (bf16)rb[2].w, (bf16)rb[3].w};
        *(bf16x4*)&Bs[s][swz16(nn + 0, k4)] = p0;
        *(bf16x4*)&Bs[s][swz16(nn + 1, k4)] = p1;
        *(bf16x4*)&Bs[s][swz16(nn + 2, k4)] = p2;
        *(bf16x4*)&Bs[s][swz16(nn + 3, k4)] = p3;
    };
    auto MM = [&](int cur) {
        __builtin_amdgcn_s_setprio(1);
        #pragma unroll
        for (int ks = 0; ks < 2; ++ks) {
            bf16x8 a0 = *(const bf16x8*)&As[cur][aoff[0][ks]];
            bf16x8 a1 = *(const bf16x8*)&As[cur][aoff[1][ks]];
            bf16x8 b0 = *(const bf16x8*)&Bs[cur][boff[0][ks]];
            bf16x8 b1 = *(const bf16x8*)&Bs[cur][boff[1][ks]];
            acc[0][0] = __builtin_amdgcn_mfma_f32_32x32x16_bf16(a0, b0, acc[0][0], 0, 0, 0);
            acc[1][0] = __builtin_amdgcn_mfma_f32_32x32x16_bf16(a1, b0, acc[1][0], 0, 0, 0);
            acc[0][1] = __builtin_amdgcn_mfma_f32_32x32x16_bf16(a0, b1, acc[0][1], 0, 0, 0);
            acc[1][1] = __builtin_amdgcn_mfma_f32_32x32x16_bf16(a1, b1, acc[1][1], 0, 0, 0);
        }
        __builtin_amdgcn_s_setprio(0);
    };

    const int NT = F_INT / 32;   // 44
    GLLA(0, 0);
    __builtin_amdgcn_sched_barrier(0);
    LOADB(0);
    WRITEB(0);
    LOADB(1);
    WAITBAR();

    for (int kt = 0; kt < NT; ++kt) {
        int cur = kt & 1, nxt = cur ^ 1;
        int t1 = kt + 1 < NT ? kt + 1 : NT - 1;
        int t2 = kt + 2 < NT ? kt + 2 : NT - 1;
        GLLA(nxt, t1);
        __builtin_amdgcn_sched_barrier(0);
        WRITEB(nxt);
        LOADB(t2);
        MM(cur);
        WAITBAR();
    }

    int colg = n0 + wn + (lane & 31);
    #pragma unroll
    for (int mf = 0; mf < 2; ++mf) {
        #pragma unroll
        for (int nf = 0; nf < 2; ++nf) {
            #pragma unroll
            for (int r = 0; r < 16; ++r) {
                int row = (r & 3) + 8 * (r >> 2) + 4 * hk;
                int grow = m0 + wm + mf * 32 + row;
                if (grow < cnt)
                    P[(size_t)(base + grow) * D_HID + colg + nf * 32] = (bf16)acc[mf][nf][r];
            }
        }
    }
}

// ---------------- combine ----------------
__global__ __launch_bounds__(256) void k_combine(const bf16* __restrict__ P,
                                                 const int* __restrict__ slots,
                                                 const float* __restrict__ tok_w,
                                                 float* __restrict__ out) {
    int t = blockIdx.x;
    int tid = threadIdx.x;
    __shared__ int ss[TOPK];
    __shared__ float ww[TOPK];
    if (tid < TOPK) { ss[tid] = slots[t * TOPK + tid]; ww[tid] = tok_w[t * TOPK + tid]; }
    __syncthreads();
    int c0 = tid * 8;
    float acc[8];
    {
        bf16x8 v0 = *(const bf16x8*)(P + (size_t)(SH_BASE + t) * D_HID + c0);
        bf16x8 v1 = *(const bf16x8*)(P + (size_t)(SH_BASE + T_TOK + t) * D_HID + c0);
        #pragma unroll
        for (int i = 0; i < 8; ++i) acc[i] = (float)v0[i] + (float)v1[i];
    }
    #pragma unroll
    for (int k = 0; k < TOPK; ++k) {
        bf16x8 v = *(const bf16x8*)(P + (size_t)ss[k] * D_HID + c0);
        float w = ww[k];
        #pragma unroll
        for (int i = 0; i < 8; ++i) acc[i] += w * (float)v[i];
    }
    float4 o0 = {acc[0], acc[1], acc[2], acc[3]};
    float4 o1 = {acc[4], acc[5], acc[6], acc[7]};
    *(float4*)(out + (size_t)t * D_HID + c0) = o0;
    *(float4*)(out + (size_t)t * D_HID + c0 + 4) = o1;
}

extern "C" void kernel_launch(void* const* d_in, const int* in_sizes, int n_in,
                              void* d_out, int out_size, void* d_ws, size_t ws_size,
                              hipStream_t stream) {
    const float* x  = (const float*)d_in[0];
    const float* wr = (const float*)d_in[1];
    const float* wg = (const float*)d_in[2];
    const float* wu = (const float*)d_in[3];
    const float* wd = (const float*)d_in[4];
    const float* sg = (const float*)d_in[5];
    const float* su = (const float*)d_in[6];
    const float* sd = (const float*)d_in[7];
    float* out = (float*)d_out;

    const size_t H_BYTES  = (size_t)ROWS_TOTAL * F_INT * 2;
    const size_t P_BYTES  = (size_t)ROWS_TOTAL * D_HID * 2;
    const size_t XP_BYTES = (size_t)XP_ROWS * D_HID * 2;

    char* w = (char*)d_ws;
    int*   counts   = (int*)(w + 0);
    int*   cursors  = (int*)(w + 256);
    int*   offs     = (int*)(w + 512);
    int*   tok_e    = (int*)(w + 8192);
    float* tok_w    = (float*)(w + 8192 + 49152);
    int*   slots    = (int*)(w + 8192 + 2 * 49152);
    int*   rowtok   = (int*)(w + 8192 + 3 * 49152);
    bf16*  H        = (bf16*)(w + 262144);
    bf16*  P        = (bf16*)(w + 262144 + H_BYTES);
    bf16*  Xp       = (bf16*)(w + 262144 + H_BYTES + P_BYTES);

    int dense = (ws_size >= 262144 + H_BYTES + P_BYTES + XP_BYTES) ? 1 : 0;

    hipMemsetAsync(counts, 0, 128, stream);
    k_router<<<T_TOK, 256, 0, stream>>>(x, wr, counts, tok_e, tok_w);
    k_plan<<<1, 64, 0, stream>>>(counts, offs, cursors);
    k_assign<<<T_TOK / 256, 256, 0, stream>>>(tok_e, offs, cursors, slots, rowtok);
    if (dense) {
        k_gather<<<XP_ROWS, 256, 0, stream>>>(x, rowtok, Xp);
    } else {
        k_xcvt<<<T_TOK * D_HID / 2048, 256, 0, stream>>>(x, Xp);
    }
    k_gateup<<<MAXT_GU * GU_NBN, 256, 0, stream>>>(
        Xp, wg, wu, sg, su, rowtok, counts, offs, H, dense);
    k_down<<<MAXT_DN * (D_HID / 128), 256, 0, stream>>>(
        H, wd, sd, counts, offs, P);
    k_combine<<<T_TOK, 256, 0, stream>>>(P, slots, tok_w, out);
}

// Round 15
// 743.061 us; speedup vs baseline: 1.4043x; 1.0139x over previous
//
#include <hip/hip_runtime.h>
#include <hip/hip_bf16.h>

#define T_TOK 2048
#define D_HID 2048
#define F_INT 1408
#define N_EXP 32
#define TOPK 6
#define NJOBS 34
#define SH_BASE 12288
#define ROWS_TOTAL 16384
#define XP_ROWS 14336
#define MAXT_GU 159
#define GU_NBN 22
#define MAXT_DN 159
#define LDSW 40                // B LDS row stride (80 B)

typedef __bf16 bf16;
typedef __bf16 bf16x4 __attribute__((ext_vector_type(4)));
typedef __bf16 bf16x8 __attribute__((ext_vector_type(8)));
typedef float f32x4 __attribute__((ext_vector_type(4)));

// counted-vmcnt barrier: 2 gll retired, 4 B-loads stay in flight
#define WAITBAR() asm volatile("s_waitcnt vmcnt(4) lgkmcnt(0)\n\ts_barrier" ::: "memory")

__device__ __forceinline__ void gll16(const bf16* g, bf16* l) {
    __builtin_amdgcn_global_load_lds((const __attribute__((address_space(1))) void*)g,
                                     (__attribute__((address_space(3))) void*)l, 16, 0, 0);
}

// B swizzle (R8-verified)
__device__ __forceinline__ int swz16(int r, int k) {
    return r * LDSW + ((((k >> 3) ^ ((r >> 3) & 3) ^ ((r >> 5) & 3)) & 3) << 3) + (k & 7);
}
// A linear-layout slot permutation: frag reads at b128 floor
__device__ __forceinline__ int aslot(int r) { return (r + (r >> 2)) & 3; }

__device__ __forceinline__ int decode_tile(const int* __restrict__ counts, int bid,
                                           int NBN, int MSH, int NSH,
                                           int& job, int& n0, int& m0) {
    int total = 0;
    for (int j = 0; j < NJOBS; ++j) {
        int c = (j < N_EXP) ? counts[j] : T_TOK;
        total += ((c + (1 << MSH) - 1) >> MSH) * NBN;
    }
    if (bid >= total) return 0;
    int q = total >> 3, r = total & 7, x = bid & 7, o = bid >> 3;
    int L = (x < r ? x * (q + 1) : r * (q + 1) + (x - r) * q) + o;
    int acc = 0;
    for (int j = 0; j < NJOBS; ++j) {
        int c = (j < N_EXP) ? counts[j] : T_TOK;
        int tc = (c + (1 << MSH) - 1) >> MSH;
        int b = tc * NBN;
        if (L < acc + b) {
            int rem = L - acc;
            int n0i = rem / tc;
            job = j;
            n0 = n0i << NSH;
            m0 = (rem - n0i * tc) << MSH;
            return 1;
        }
        acc += b;
    }
    return 0;
}

// ---------------- router ----------------
__global__ __launch_bounds__(256) void k_router(const float* __restrict__ x,
                                                const float* __restrict__ wr,
                                                int* __restrict__ counts,
                                                int* __restrict__ tok_e,
                                                float* __restrict__ tok_w) {
    int t = blockIdx.x;
    int tid = threadIdx.x;
    __shared__ float xs[D_HID];
    __shared__ float part[8][32];
    __shared__ float probs[N_EXP];

    const float4* xsrc = (const float4*)(x + (size_t)t * D_HID);
    float4* xdst = (float4*)xs;
    for (int i = tid; i < D_HID / 4; i += 256) xdst[i] = xsrc[i];
    __syncthreads();

    int e = tid & 31, c = tid >> 5;
    float p = 0.f;
    const float* wp = wr + e;
    #pragma unroll 8
    for (int h = c * 256; h < c * 256 + 256; ++h) p += xs[h] * wp[h * 32];
    part[c][e] = p;
    __syncthreads();

    if (tid < 32) {
        float l = 0.f;
        #pragma unroll
        for (int cc = 0; cc < 8; ++cc) l += part[cc][tid];
        float m = l;
        for (int off = 16; off; off >>= 1) m = fmaxf(m, __shfl_xor(m, off));
        float ex = __expf(l - m);
        float s = ex;
        for (int off = 16; off; off >>= 1) s += __shfl_xor(s, off);
        probs[tid] = ex / s;
    }
    __syncthreads();

    if (tid == 0) {
        unsigned used = 0;
        int ids[TOPK]; float wsv[TOPK]; float wsum = 0.f;
        for (int k = 0; k < TOPK; ++k) {
            int best = 0; float bv = -1.f;
            for (int ee = 0; ee < N_EXP; ++ee)
                if (!((used >> ee) & 1u) && probs[ee] > bv) { bv = probs[ee]; best = ee; }
            used |= 1u << best;
            ids[k] = best; wsv[k] = bv; wsum += bv;
        }
        float inv = 1.f / wsum;
        for (int k = 0; k < TOPK; ++k) {
            tok_e[t * TOPK + k] = ids[k];
            tok_w[t * TOPK + k] = wsv[k] * inv;
            atomicAdd(&counts[ids[k]], 1);
        }
    }
}

// ---------------- plan ----------------
__global__ void k_plan(const int* __restrict__ counts, int* __restrict__ offs,
                       int* __restrict__ cursors) {
    int tid = threadIdx.x;
    if (tid < N_EXP) cursors[tid] = 0;
    if (tid == 0) {
        int o = 0;
        offs[0] = 0;
        for (int e2 = 0; e2 < N_EXP; ++e2) { o += counts[e2]; offs[e2 + 1] = o; }
        offs[33] = offs[32] + T_TOK;
        offs[34] = offs[33] + T_TOK;
    }
}

// ---------------- assign ----------------
__global__ __launch_bounds__(256) void k_assign(const int* __restrict__ tok_e,
                                                const int* __restrict__ offs,
                                                int* __restrict__ cursors,
                                                int* __restrict__ slots,
                                                int* __restrict__ rowtok) {
    int t = blockIdx.x * 256 + threadIdx.x;
    #pragma unroll
    for (int k = 0; k < TOPK; ++k) {
        int e = tok_e[t * TOPK + k];
        int pos = atomicAdd(&cursors[e], 1);
        int slot = offs[e] + pos;
        slots[t * TOPK + k] = slot;
        rowtok[slot] = t;
    }
    rowtok[SH_BASE + t] = t;
    rowtok[SH_BASE + T_TOK + t] = t;
}

// ---------------- gather+cvt ----------------
__global__ __launch_bounds__(256) void k_gather(const float* __restrict__ x,
                                                const int* __restrict__ rowtok,
                                                bf16* __restrict__ Xp) {
    int s = blockIdx.x;
    int src = (s < SH_BASE) ? rowtok[s] : (s - SH_BASE);
    const float* xr = x + (size_t)src * D_HID + threadIdx.x * 8;
    float4 f0 = *(const float4*)xr;
    float4 f1 = *(const float4*)(xr + 4);
    bf16x8 v = {(bf16)f0.x, (bf16)f0.y, (bf16)f0.z, (bf16)f0.w,
                (bf16)f1.x, (bf16)f1.y, (bf16)f1.z, (bf16)f1.w};
    *(bf16x8*)(Xp + (size_t)s * D_HID + threadIdx.x * 8) = v;
}

__global__ __launch_bounds__(256) void k_xcvt(const float* __restrict__ x,
                                              bf16* __restrict__ xb) {
    int i = blockIdx.x * 2048 + threadIdx.x * 8;
    float4 f0 = *(const float4*)(x + i);
    float4 f1 = *(const float4*)(x + i + 4);
    bf16x8 v = {(bf16)f0.x, (bf16)f0.y, (bf16)f0.z, (bf16)f0.w,
                (bf16)f1.x, (bf16)f1.y, (bf16)f1.z, (bf16)f1.w};
    *(bf16x8*)(xb + i) = v;
}

// ---------------- GEMM1: H = silu(X Wg) * (X Wu) ----------------
// BM=128 x BN=64, BK=32, 4 waves (wave 64x32 of both mats, acc=64 AGPR).
// A: global_load_lds (linear+slot-permuted source), counted vmcnt(4) barrier.
__global__ __launch_bounds__(256, 4) void k_gateup(
    const bf16* __restrict__ xp, const float* __restrict__ wg, const float* __restrict__ wu,
    const float* __restrict__ sg, const float* __restrict__ su,
    const int* __restrict__ rowtok, const int* __restrict__ counts, const int* __restrict__ offs,
    bf16* __restrict__ H, int dense) {

    int job, n0, m0;
    if (!decode_tile(counts, blockIdx.x, GU_NBN, 7, 6, job, n0, m0)) return;
    int cnt = (job < N_EXP) ? counts[job] : T_TOK;
    int base = offs[job];
    const float* Wg = (job < N_EXP) ? wg + (size_t)job * D_HID * F_INT
                                    : sg + (size_t)(job - N_EXP) * D_HID * F_INT;
    const float* Wu = (job < N_EXP) ? wu + (size_t)job * D_HID * F_INT
                                    : su + (size_t)(job - N_EXP) * D_HID * F_INT;

    __shared__ bf16 As[2][128 * 32];         // linear A (gll dest), 16 KB
    __shared__ bf16 Bg[2][64 * LDSW];        // 10 KB
    __shared__ bf16 Bu[2][64 * LDSW];        // 10 KB

    int tid = threadIdx.x;
    int lane = tid & 63;
    int wid = tid >> 6;
    int wm = (wid & 1) * 64;
    int wn = (wid >> 1) * 32;

    // per-lane gll A sources (2 instrs/wave: 16 rows each)
    const bf16* agsrc[2];
    #pragma unroll
    for (int i = 0; i < 2; ++i) {
        int rl = wid * 32 + i * 16 + (lane >> 2);
        int grow = m0 + rl; if (grow > cnt - 1) grow = cnt - 1;
        int arow = dense ? (((job < N_EXP) ? base : SH_BASE) + grow)
                         : rowtok[base + grow];
        int kslot = (lane & 3) ^ aslot(rl);
        agsrc[i] = xp + (size_t)arow * D_HID + kslot * 8;
    }

    // B staging: half threads Wg / half Wu; n-fastest (coalesced 256B/16 lanes).
    int sub = tid & 127;
    int nn = (sub & 15) * 4;
    int k4 = (sub >> 4) * 4;
    const float* wsrc = ((tid & 128) ? Wu : Wg) + (size_t)k4 * F_INT + n0 + nn;

    // precomputed fragment offsets (loop-invariant)
    int q = lane >> 4;
    int aoff[4], boff[2];
    #pragma unroll
    for (int mf = 0; mf < 4; ++mf) {
        int R = wm + mf * 16 + (lane & 15);
        aoff[mf] = R * 32 + ((q ^ aslot(R)) << 3);
    }
    #pragma unroll
    for (int nf = 0; nf < 2; ++nf)
        boff[nf] = swz16(wn + nf * 16 + (lane & 15), q * 8);

    f32x4 accg[4][2], accu[4][2];
    f32x4 zero = {0.f, 0.f, 0.f, 0.f};
    #pragma unroll
    for (int i = 0; i < 4; ++i)
        #pragma unroll
        for (int j = 0; j < 2; ++j) { accg[i][j] = zero; accu[i][j] = zero; }

    float4 rb[4];

    auto GLLA = [&](int s, int t) {
        gll16(agsrc[0] + t * 32, &As[s][wid * 1024]);
        gll16(agsrc[1] + t * 32, &As[s][wid * 1024 + 512]);
    };
    auto LOADB = [&](int t) {
        const float* b0 = wsrc + (size_t)(t * 32) * F_INT;
        rb[0] = *(const float4*)b0;
        rb[1] = *(const float4*)(b0 + F_INT);
        rb[2] = *(const float4*)(b0 + 2 * F_INT);
        rb[3] = *(const float4*)(b0 + 3 * F_INT);
    };
    auto WRITEB = [&](int s) {
        bf16* bd = (tid & 128) ? Bu[s] : Bg[s];
        bf16x4 p0 = {(bf16)rb[0].x, (bf16)rb[1].x, (bf16)rb[2].x, (bf16)rb[3].x};
        bf16x4 p1 = {(bf16)rb[0].y, (bf16)rb[1].y, (bf16)rb[2].y, (bf16)rb[3].y};
        bf16x4 p2 = {(bf16)rb[0].z, (bf16)rb[1].z, (bf16)rb[2].z, (bf16)rb[3].z};
        bf16x4 p3 = {(bf16)rb[0].w, (bf16)rb[1].w, (bf16)rb[2].w, (bf16)rb[3].w};
        *(bf16x4*)&bd[swz16(nn + 0, k4)] = p0;
        *(bf16x4*)&bd[swz16(nn + 1, k4)] = p1;
        *(bf16x4*)&bd[swz16(nn + 2, k4)] = p2;
        *(bf16x4*)&bd[swz16(nn + 3, k4)] = p3;
    };
    auto MM = [&](int cur) {
        bf16x8 af[4];
        #pragma unroll
        for (int mf = 0; mf < 4; ++mf)
            af[mf] = *(const bf16x8*)&As[cur][aoff[mf]];
        #pragma unroll
        for (int nf = 0; nf < 2; ++nf) {
            bf16x8 bfr = *(const bf16x8*)&Bg[cur][boff[nf]];
            bf16x8 ufr = *(const bf16x8*)&Bu[cur][boff[nf]];
            #pragma unroll
            for (int mf = 0; mf < 4; ++mf) {
                accg[mf][nf] = __builtin_amdgcn_mfma_f32_16x16x32_bf16(af[mf], bfr, accg[mf][nf], 0, 0, 0);
                accu[mf][nf] = __builtin_amdgcn_mfma_f32_16x16x32_bf16(af[mf], ufr, accu[mf][nf], 0, 0, 0);
            }
        }
    };

    const int NT = D_HID / 32;   // 64
    // prologue
    GLLA(0, 0);
    __builtin_amdgcn_sched_barrier(0);
    LOADB(0);
    WRITEB(0);                   // compiler drains to vmcnt(0) here (prologue only)
    LOADB(1);
    WAITBAR();

    for (int kt = 0; kt < NT; ++kt) {
        int cur = kt & 1, nxt = cur ^ 1;
        int t1 = kt + 1 < NT ? kt + 1 : NT - 1;
        int t2 = kt + 2 < NT ? kt + 2 : NT - 1;
        GLLA(nxt, t1);                          // 2 gll into nxt (A)
        __builtin_amdgcn_sched_barrier(0);      // keep loadB AFTER gll in vmcnt FIFO
        WRITEB(nxt);                            // B tile kt+1 from rb (auto vmcnt(2))
        LOADB(t2);                              // refill rb, stays in flight over barrier
        MM(cur);
        WAITBAR();                              // vmcnt(4): gll retired, 4 B-loads live
    }

    // epilogue: h = silu(g) * u
    #pragma unroll
    for (int mf = 0; mf < 4; ++mf) {
        #pragma unroll
        for (int nf = 0; nf < 2; ++nf) {
            int col = n0 + wn + nf * 16 + (lane & 15);
            #pragma unroll
            for (int r = 0; r < 4; ++r) {
                int grow = m0 + wm + mf * 16 + (lane >> 4) * 4 + r;
                if (grow < cnt) {
                    float g = accg[mf][nf][r];
                    float u = accu[mf][nf][r];
                    float h = g * u / (1.f + __expf(-g));
                    H[(size_t)(base + grow) * F_INT + col] = (bf16)h;
                }
            }
        }
    }
}

// ---------------- GEMM2: P = H Wd ----------------
__global__ __launch_bounds__(256, 4) void k_down(
    const bf16* __restrict__ H, const float* __restrict__ wd, const float* __restrict__ sd,
    const int* __restrict__ counts, const int* __restrict__ offs,
    bf16* __restrict__ P) {

    int job, n0, m0;
    if (!decode_tile(counts, blockIdx.x, D_HID / 128, 7, 7, job, n0, m0)) return;
    int cnt = (job < N_EXP) ? counts[job] : T_TOK;
    int base = offs[job];
    const float* Wd = (job < N_EXP) ? wd + (size_t)job * F_INT * D_HID
                                    : sd + (size_t)(job - N_EXP) * F_INT * D_HID;

    __shared__ bf16 As[2][128 * 32];
    __shared__ bf16 Bs[2][128 * LDSW];

    int tid = threadIdx.x;
    int lane = tid & 63;
    int wid = tid >> 6;
    int wm = (wid >> 1) * 64;
    int wn = (wid & 1) * 64;

    const bf16* agsrc[2];
    #pragma unroll
    for (int i = 0; i < 2; ++i) {
        int rl = wid * 32 + i * 16 + (lane >> 2);
        int grow = m0 + rl; if (grow > cnt - 1) grow = cnt - 1;
        int kslot = (lane & 3) ^ aslot(rl);
        agsrc[i] = H + (size_t)(base + grow) * F_INT + kslot * 8;
    }

    int k4 = (tid >> 5) * 4;
    int nn = (tid & 31) * 4;
    const float* bsrc = Wd + (size_t)k4 * D_HID + n0 + nn;

    int q = lane >> 4;
    int aoff[4], boff[4];
    #pragma unroll
    for (int mf = 0; mf < 4; ++mf) {
        int R = wm + mf * 16 + (lane & 15);
        aoff[mf] = R * 32 + ((q ^ aslot(R)) << 3);
    }
    #pragma unroll
    for (int nf = 0; nf < 4; ++nf)
        boff[nf] = swz16(wn + nf * 16 + (lane & 15), q * 8);

    f32x4 acc[4][4];
    f32x4 zero = {0.f, 0.f, 0.f, 0.f};
    #pragma unroll
    for (int i = 0; i < 4; ++i)
        #pragma unroll
        for (int j = 0; j < 4; ++j) acc[i][j] = zero;

    float4 rb[4];

    auto GLLA = [&](int s, int t) {
        gll16(agsrc[0] + t * 32, &As[s][wid * 1024]);
        gll16(agsrc[1] + t * 32, &As[s][wid * 1024 + 512]);
    };
    auto LOADB = [&](int t) {
        const float* b0 = bsrc + (size_t)(t * 32) * D_HID;
        rb[0] = *(const float4*)b0;
        rb[1] = *(const float4*)(b0 + D_HID);
        rb[2] = *(const float4*)(b0 + 2 * D_HID);
        rb[3] = *(const float4*)(b0 + 3 * D_HID);
    };
    auto WRITEB = [&](int s) {
        bf16x4 p0 = {(bf16)rb[0].x, (bf16)rb[1].x, (bf16)rb[2].x, (bf16)rb[3].x};
        bf16x4 p1 = {(bf16)rb[0].y, (bf16)rb[1].y, (bf16)rb[2].y, (bf16)rb[3].y};
        bf16x4 p2 = {(bf16)rb[0].z, (bf16)rb[1].z, (bf16)rb[2].z, (bf16)rb[3].z};
        bf16x4 p3 = {(bf16)rb[0].w, (bf16)rb[1].w, (bf16)rb[2].w, (bf16)rb[3].w};
        *(bf16x4*)&Bs[s][swz16(nn + 0, k4)] = p0;
        *(bf16x4*)&Bs[s][swz16(nn + 1, k4)] = p1;
        *(bf16x4*)&Bs[s][swz16(nn + 2, k4)] = p2;
        *(bf16x4*)&Bs[s][swz16(nn + 3, k4)] = p3;
    };
    auto MM = [&](int cur) {
        bf16x8 af[4];
        #pragma unroll
        for (int mf = 0; mf < 4; ++mf)
            af[mf] = *(const bf16x8*)&As[cur][aoff[mf]];
        #pragma unroll
        for (int nf = 0; nf < 4; ++nf) {
            bf16x8 bfr = *(const bf16x8*)&Bs[cur][boff[nf]];
            #pragma unroll
            for (int mf = 0; mf < 4; ++mf)
                acc[mf][nf] = __builtin_amdgcn_mfma_f32_16x16x32_bf16(af[mf], bfr, acc[mf][nf], 0, 0, 0);
        }
    };

    const int NT = F_INT / 32;   // 44
    GLLA(0, 0);
    __builtin_amdgcn_sched_barrier(0);
    LOADB(0);
    WRITEB(0);
    LOADB(1);
    WAITBAR();

    for (int kt = 0; kt < NT; ++kt) {
        int cur = kt & 1, nxt = cur ^ 1;
        int t1 = kt + 1 < NT ? kt + 1 : NT - 1;
        int t2 = kt + 2 < NT ? kt + 2 : NT - 1;
        GLLA(nxt, t1);
        __builtin_amdgcn_sched_barrier(0);
        WRITEB(nxt);
        LOADB(t2);
        MM(cur);
        WAITBAR();
    }

    #pragma unroll
    for (int mf = 0; mf < 4; ++mf) {
        #pragma unroll
        for (int nf = 0; nf < 4; ++nf) {
            int col = n0 + wn + nf * 16 + (lane & 15);
            #pragma unroll
            for (int r = 0; r < 4; ++r) {
                int grow = m0 + wm + mf * 16 + (lane >> 4) * 4 + r;
                if (grow < cnt)
                    P[(size_t)(base + grow) * D_HID + col] = (bf16)acc[mf][nf][r];
            }
        }
    }
}

// ---------------- combine ----------------
__global__ __launch_bounds__(256) void k_combine(const bf16* __restrict__ P,
                                                 const int* __restrict__ slots,
                                                 const float* __restrict__ tok_w,
                                                 float* __restrict__ out) {
    int t = blockIdx.x;
    int tid = threadIdx.x;
    __shared__ int ss[TOPK];
    __shared__ float ww[TOPK];
    if (tid < TOPK) { ss[tid] = slots[t * TOPK + tid]; ww[tid] = tok_w[t * TOPK + tid]; }
    __syncthreads();
    int c0 = tid * 8;
    float acc[8];
    {
        bf16x8 v0 = *(const bf16x8*)(P + (size_t)(SH_BASE + t) * D_HID + c0);
        bf16x8 v1 = *(const bf16x8*)(P + (size_t)(SH_BASE + T_TOK + t) * D_HID + c0);
        #pragma unroll
        for (int i = 0; i < 8; ++i) acc[i] = (float)v0[i] + (float)v1[i];
    }
    #pragma unroll
    for (int k = 0; k < TOPK; ++k) {
        bf16x8 v = *(const bf16x8*)(P + (size_t)ss[k] * D_HID + c0);
        float w = ww[k];
        #pragma unroll
        for (int i = 0; i < 8; ++i) acc[i] += w * (float)v[i];
    }
    float4 o0 = {acc[0], acc[1], acc[2], acc[3]};
    float4 o1 = {acc[4], acc[5], acc[6], acc[7]};
    *(float4*)(out + (size_t)t * D_HID + c0) = o0;
    *(float4*)(out + (size_t)t * D_HID + c0 + 4) = o1;
}

extern "C" void kernel_launch(void* const* d_in, const int* in_sizes, int n_in,
                              void* d_out, int out_size, void* d_ws, size_t ws_size,
                              hipStream_t stream) {
    const float* x  = (const float*)d_in[0];
    const float* wr = (const float*)d_in[1];
    const float* wg = (const float*)d_in[2];
    const float* wu = (const float*)d_in[3];
    const float* wd = (const float*)d_in[4];
    const float* sg = (const float*)d_in[5];
    const float* su = (const float*)d_in[6];
    const float* sd = (const float*)d_in[7];
    float* out = (float*)d_out;

    const size_t H_BYTES  = (size_t)ROWS_TOTAL * F_INT * 2;
    const size_t P_BYTES  = (size_t)ROWS_TOTAL * D_HID * 2;
    const size_t XP_BYTES = (size_t)XP_ROWS * D_HID * 2;

    char* w = (char*)d_ws;
    int*   counts   = (int*)(w + 0);
    int*   cursors  = (int*)(w + 256);
    int*   offs     = (int*)(w + 512);
    int*   tok_e    = (int*)(w + 8192);
    float* tok_w    = (float*)(w + 8192 + 49152);
    int*   slots    = (int*)(w + 8192 + 2 * 49152);
    int*   rowtok   = (int*)(w + 8192 + 3 * 49152);
    bf16*  H        = (bf16*)(w + 262144);
    bf16*  P        = (bf16*)(w + 262144 + H_BYTES);
    bf16*  Xp       = (bf16*)(w + 262144 + H_BYTES + P_BYTES);

    int dense = (ws_size >= 262144 + H_BYTES + P_BYTES + XP_BYTES) ? 1 : 0;

    hipMemsetAsync(counts, 0, 128, stream);
    k_router<<<T_TOK, 256, 0, stream>>>(x, wr, counts, tok_e, tok_w);
    k_plan<<<1, 64, 0, stream>>>(counts, offs, cursors);
    k_assign<<<T_TOK / 256, 256, 0, stream>>>(tok_e, offs, cursors, slots, rowtok);
    if (dense) {
        k_gather<<<XP_ROWS, 256, 0, stream>>>(x, rowtok, Xp);
    } else {
        k_xcvt<<<T_TOK * D_HID / 2048, 256, 0, stream>>>(x, Xp);
    }
    k_gateup<<<MAXT_GU * GU_NBN, 256, 0, stream>>>(
        Xp, wg, wu, sg, su, rowtok, counts, offs, H, dense);
    k_down<<<MAXT_DN * (D_HID / 128), 256, 0, stream>>>(
        H, wd, sd, counts, offs, P);
    k_combine<<<T_TOK, 256, 0, stream>>>(P, slots, tok_w, out);
}